// Round 4
// baseline (13448.640 us; speedup 1.0000x reference)
//
#include <hip/hip_runtime.h>
#include <math.h>

#define N_ 32
#define C_ 512
#define CR_ 64
#define HW_ 3136
#define HW4_ 784
constexpr float EPS = 1e-5f;

typedef float f4 __attribute__((ext_vector_type(4)));

// One block per (n,c) row. The row lives in registers for the whole kernel:
// pool it, participate in the per-sample gate rendezvous, then scale+store it.
// ws layout: pooled[N_*C_] | gate[N_*C_] | cnt[N_] | flag[N_]
__global__ __launch_bounds__(256) void fused_kernel(
    const float* __restrict__ x,
    const float* __restrict__ w1, const float* __restrict__ b1,
    const float* __restrict__ gn1_w, const float* __restrict__ gn1_b,
    const float* __restrict__ w2, const float* __restrict__ b2,
    const float* __restrict__ gn2_w, const float* __restrict__ gn2_b,
    float* __restrict__ pooled, float* __restrict__ gate,
    int* __restrict__ cnt, int* __restrict__ flag,
    float* __restrict__ out)
{
    const int row = blockIdx.x;        // n*C_ + c
    const int n = row >> 9;            // row / 512
    const int tid = threadIdx.x;

    const f4* xr = reinterpret_cast<const f4*>(x + (size_t)row * HW_);
    f4* orow = reinterpret_cast<f4*>(out + (size_t)row * HW_);

    // ---- load the whole row into registers (784 f4 across 256 threads) ----
    f4 v0 = xr[tid];
    f4 v1 = xr[tid + 256];
    f4 v2 = xr[tid + 512];
    f4 v3;
    const bool has4 = tid < (HW4_ - 768);   // threads 0..15 take the tail
    if (has4) v3 = xr[tid + 768];

    // ---- pool: block-reduce the row sum ----
    float acc = (v0.x + v0.y + v0.z + v0.w)
              + (v1.x + v1.y + v1.z + v1.w)
              + (v2.x + v2.y + v2.z + v2.w);
    if (has4) acc += v3.x + v3.y + v3.z + v3.w;
    for (int o = 32; o; o >>= 1) acc += __shfl_down(acc, o, 64);
    __shared__ float sred[4];
    __shared__ int lastFlag;
    if ((tid & 63) == 0) sred[tid >> 6] = acc;
    __syncthreads();
    if (tid == 0) {
        const float m = (sred[0] + sred[1] + sred[2] + sred[3]) * (1.0f / HW_);
        __hip_atomic_store(&pooled[row], m, __ATOMIC_RELAXED, __HIP_MEMORY_SCOPE_AGENT);
        const int old = __hip_atomic_fetch_add(&cnt[n], 1, __ATOMIC_ACQ_REL,
                                               __HIP_MEMORY_SCOPE_AGENT);
        lastFlag = (old == C_ - 1);
    }
    __syncthreads();

    if (lastFlag) {
        // ---- last arrival of sample n computes the whole gate ----
        __shared__ float sp[C_];
        __shared__ float sh[CR_];
        sp[tid] = __hip_atomic_load(&pooled[n * C_ + tid],
                                    __ATOMIC_RELAXED, __HIP_MEMORY_SCOPE_AGENT);
        sp[tid + 256] = __hip_atomic_load(&pooled[n * C_ + tid + 256],
                                          __ATOMIC_RELAXED, __HIP_MEMORY_SCOPE_AGENT);
        __syncthreads();

        // h[r] = dot(sp, w1[r,:]) + b1[r] ; 4 threads per output r
        {
            const int r = tid >> 2, l4 = tid & 3;
            float a = 0.f;
            for (int c = l4; c < C_; c += 4) a += sp[c] * w1[r * C_ + c];
            a += __shfl_xor(a, 1, 64);
            a += __shfl_xor(a, 2, 64);
            if (l4 == 0) sh[r] = a + b1[r];
        }
        __syncthreads();

        // GroupNorm(1) over 64 + ELU (first wave)
        if (tid < 64) {
            const float v = sh[tid];
            float s = v;
            for (int o = 32; o; o >>= 1) s += __shfl_xor(s, o, 64);
            const float mu = s * (1.0f / CR_);
            const float d = v - mu;
            float vv = d * d;
            for (int o = 32; o; o >>= 1) vv += __shfl_xor(vv, o, 64);
            float xn = d * rsqrtf(vv * (1.0f / CR_) + EPS) * gn1_w[tid] + gn1_b[tid];
            sh[tid] = xn > 0.f ? xn : expm1f(xn);  // ELU alpha=1
        }
        __syncthreads();

        // g[c] for c = tid and tid+256
        float g0 = b2[tid], g1 = b2[tid + 256];
        #pragma unroll 8
        for (int r = 0; r < CR_; ++r) {
            g0 += sh[r] * w2[tid * CR_ + r];
            g1 += sh[r] * w2[(tid + 256) * CR_ + r];
        }
        // GroupNorm(1) over 512 (2 values per thread, 4 waves)
        float s = g0 + g1;
        for (int o = 32; o; o >>= 1) s += __shfl_xor(s, o, 64);
        if ((tid & 63) == 0) sred[tid >> 6] = s;
        __syncthreads();
        const float mu = (sred[0] + sred[1] + sred[2] + sred[3]) * (1.0f / C_);
        const float d0 = g0 - mu, d1 = g1 - mu;
        float vv = d0 * d0 + d1 * d1;
        for (int o = 32; o; o >>= 1) vv += __shfl_xor(vv, o, 64);
        __syncthreads();
        if ((tid & 63) == 0) sred[tid >> 6] = vv;
        __syncthreads();
        const float rstd = rsqrtf((sred[0] + sred[1] + sred[2] + sred[3]) * (1.0f / C_) + EPS);
        const float xn0 = d0 * rstd * gn2_w[tid] + gn2_b[tid];
        const float xn1 = d1 * rstd * gn2_w[tid + 256] + gn2_b[tid + 256];
        __hip_atomic_store(&gate[n * C_ + tid], 1.f / (1.f + expf(-xn0)),
                           __ATOMIC_RELAXED, __HIP_MEMORY_SCOPE_AGENT);
        __hip_atomic_store(&gate[n * C_ + tid + 256], 1.f / (1.f + expf(-xn1)),
                           __ATOMIC_RELAXED, __HIP_MEMORY_SCOPE_AGENT);
        __syncthreads();
        if (tid == 0)
            __hip_atomic_store(&flag[n], 1, __ATOMIC_RELEASE, __HIP_MEMORY_SCOPE_AGENT);
    } else {
        // ---- wait for the gate of our sample ----
        if (tid == 0) {
            while (__hip_atomic_load(&flag[n], __ATOMIC_ACQUIRE,
                                     __HIP_MEMORY_SCOPE_AGENT) == 0) {
                __builtin_amdgcn_s_sleep(16);
            }
        }
        __syncthreads();
    }

    // ---- scale the register-resident row and store (non-temporal) ----
    const float g = __hip_atomic_load(&gate[row], __ATOMIC_RELAXED,
                                      __HIP_MEMORY_SCOPE_AGENT);
    v0 *= g; v1 *= g; v2 *= g;
    __builtin_nontemporal_store(v0, &orow[tid]);
    __builtin_nontemporal_store(v1, &orow[tid + 256]);
    __builtin_nontemporal_store(v2, &orow[tid + 512]);
    if (has4) { v3 *= g; __builtin_nontemporal_store(v3, &orow[tid + 768]); }
}

extern "C" void kernel_launch(void* const* d_in, const int* in_sizes, int n_in,
                              void* d_out, int out_size, void* d_ws, size_t ws_size,
                              hipStream_t stream) {
    const float* x     = (const float*)d_in[0];
    const float* w1    = (const float*)d_in[1];
    const float* b1    = (const float*)d_in[2];
    const float* gn1_w = (const float*)d_in[3];
    const float* gn1_b = (const float*)d_in[4];
    const float* w2    = (const float*)d_in[5];
    const float* b2    = (const float*)d_in[6];
    const float* gn2_w = (const float*)d_in[7];
    const float* gn2_b = (const float*)d_in[8];
    float* out = (float*)d_out;

    float* pooled = (float*)d_ws;              // N_*C_ floats
    float* gate   = pooled + N_ * C_;          // N_*C_ floats
    int*   cnt    = (int*)(gate + N_ * C_);    // N_ ints
    int*   flag   = cnt + N_;                  // N_ ints

    // rendezvous state must be zero at every call (deterministic, capturable)
    hipMemsetAsync(cnt, 0, 2 * N_ * sizeof(int), stream);

    fused_kernel<<<N_ * C_, 256, 0, stream>>>(x, w1, b1, gn1_w, gn1_b,
                                              w2, b2, gn2_w, gn2_b,
                                              pooled, gate, cnt, flag, out);
}

// Round 5
// 1671.650 us; speedup vs baseline: 8.0451x; 8.0451x over previous
//
#include <hip/hip_runtime.h>
#include <math.h>

#define N_ 32
#define C_ 512
#define CR_ 64
#define HW_ 3136
#define HW4_ 784
constexpr float EPS = 1e-5f;

typedef float f4 __attribute__((ext_vector_type(4)));

#define LD_REL(p)    __hip_atomic_load((p), __ATOMIC_RELAXED, __HIP_MEMORY_SCOPE_AGENT)
#define ST_REL(p, v) __hip_atomic_store((p), (v), __ATOMIC_RELAXED, __HIP_MEMORY_SCOPE_AGENT)
#define ST_RLS(p, v) __hip_atomic_store((p), (v), __ATOMIC_RELEASE, __HIP_MEMORY_SCOPE_AGENT)

// One block per (n,c) row; the row lives in registers the whole kernel.
// Pool -> per-sample rendezvous (no RMW atomics, relaxed polling only) -> scale.
// ws: valid[16384] int | flag[32*32] int (128B stride) | pooled[16384] f | gate[16384] f
__global__ __launch_bounds__(256) void fused_kernel(
    const float* __restrict__ x,
    const float* __restrict__ w1, const float* __restrict__ b1,
    const float* __restrict__ gn1_w, const float* __restrict__ gn1_b,
    const float* __restrict__ w2, const float* __restrict__ b2,
    const float* __restrict__ gn2_w, const float* __restrict__ gn2_b,
    int* __restrict__ valid, int* __restrict__ flag,
    float* __restrict__ pooled, float* __restrict__ gate,
    float* __restrict__ out)
{
    const int row = blockIdx.x;        // n*C_ + c
    const int n = row >> 9;
    const int c = row & (C_ - 1);
    const int tid = threadIdx.x;

    const f4* xr = reinterpret_cast<const f4*>(x + (size_t)row * HW_);
    f4* orow = reinterpret_cast<f4*>(out + (size_t)row * HW_);

    // ---- load whole row into registers (784 f4 across 256 threads) ----
    f4 v0 = xr[tid];
    f4 v1 = xr[tid + 256];
    f4 v2 = xr[tid + 512];
    f4 v3;
    const bool has4 = tid < (HW4_ - 768);
    if (has4) v3 = xr[tid + 768];

    // ---- pool: block reduce ----
    float acc = (v0.x + v0.y + v0.z + v0.w)
              + (v1.x + v1.y + v1.z + v1.w)
              + (v2.x + v2.y + v2.z + v2.w);
    if (has4) acc += v3.x + v3.y + v3.z + v3.w;
    for (int o = 32; o; o >>= 1) acc += __shfl_down(acc, o, 64);
    __shared__ float sred[4];
    if ((tid & 63) == 0) sred[tid >> 6] = acc;
    __syncthreads();
    if (tid == 0) {
        const float m = (sred[0] + sred[1] + sred[2] + sred[3]) * (1.0f / HW_);
        ST_REL(&pooled[row], m);
        ST_RLS(&valid[row], 1);   // release: pooled visible before valid
    }

    if (c == C_ - 1) {
        // ---- designated gate block for sample n (last in dispatch order) ----
        __shared__ float sp[C_];
        __shared__ float sh[CR_];
        const int base = n * C_;
        // poll all 512 valid words with RELAXED loads (no invalidates)
        for (;;) {
            const int a = LD_REL(&valid[base + tid]);
            const int b = LD_REL(&valid[base + 256 + tid]);
            if (__syncthreads_and(a != 0 && b != 0)) break;
            __builtin_amdgcn_s_sleep(8);
        }
        sp[tid]       = LD_REL(&pooled[base + tid]);
        sp[tid + 256] = LD_REL(&pooled[base + 256 + tid]);
        __syncthreads();

        // h[r] = dot(sp, w1[r,:]) + b1[r] ; 4 threads per output r
        {
            const int r = tid >> 2, l4 = tid & 3;
            float a = 0.f;
            for (int cc = l4; cc < C_; cc += 4) a += sp[cc] * w1[r * C_ + cc];
            a += __shfl_xor(a, 1, 64);
            a += __shfl_xor(a, 2, 64);
            if (l4 == 0) sh[r] = a + b1[r];
        }
        __syncthreads();

        // GroupNorm(1) over 64 + ELU (first wave)
        if (tid < 64) {
            const float v = sh[tid];
            float s = v;
            for (int o = 32; o; o >>= 1) s += __shfl_xor(s, o, 64);
            const float mu = s * (1.0f / CR_);
            const float d = v - mu;
            float vv = d * d;
            for (int o = 32; o; o >>= 1) vv += __shfl_xor(vv, o, 64);
            float xn = d * rsqrtf(vv * (1.0f / CR_) + EPS) * gn1_w[tid] + gn1_b[tid];
            sh[tid] = xn > 0.f ? xn : expm1f(xn);
        }
        __syncthreads();

        // g[c] for c = tid, tid+256
        float g0 = b2[tid], g1 = b2[tid + 256];
        #pragma unroll 8
        for (int r = 0; r < CR_; ++r) {
            g0 += sh[r] * w2[tid * CR_ + r];
            g1 += sh[r] * w2[(tid + 256) * CR_ + r];
        }
        // GroupNorm(1) over 512
        float s = g0 + g1;
        for (int o = 32; o; o >>= 1) s += __shfl_xor(s, o, 64);
        if ((tid & 63) == 0) sred[tid >> 6] = s;
        __syncthreads();
        const float mu = (sred[0] + sred[1] + sred[2] + sred[3]) * (1.0f / C_);
        const float d0 = g0 - mu, d1 = g1 - mu;
        float vv = d0 * d0 + d1 * d1;
        for (int o = 32; o; o >>= 1) vv += __shfl_xor(vv, o, 64);
        __syncthreads();
        if ((tid & 63) == 0) sred[tid >> 6] = vv;
        __syncthreads();
        const float rstd = rsqrtf((sred[0] + sred[1] + sred[2] + sred[3]) * (1.0f / C_) + EPS);
        const float xn0 = d0 * rstd * gn2_w[tid] + gn2_b[tid];
        const float xn1 = d1 * rstd * gn2_w[tid + 256] + gn2_b[tid + 256];
        ST_REL(&gate[base + tid],       1.f / (1.f + expf(-xn0)));
        ST_REL(&gate[base + tid + 256], 1.f / (1.f + expf(-xn1)));
        __syncthreads();   // compiler drains vmcnt before barrier -> stores visible
        if (tid == 0) ST_RLS(&flag[n * 32], 1);
    } else {
        // ---- wait for our sample's gate: RELAXED poll + sleep, one fence ----
        if (tid == 0) {
            while (LD_REL(&flag[n * 32]) == 0) __builtin_amdgcn_s_sleep(64);
        }
        __syncthreads();
        __threadfence();
    }

    // ---- scale register-resident row, stream out ----
    const float g = LD_REL(&gate[row]);
    v0 *= g; v1 *= g; v2 *= g;
    __builtin_nontemporal_store(v0, &orow[tid]);
    __builtin_nontemporal_store(v1, &orow[tid + 256]);
    __builtin_nontemporal_store(v2, &orow[tid + 512]);
    if (has4) { v3 *= g; __builtin_nontemporal_store(v3, &orow[tid + 768]); }
}

extern "C" void kernel_launch(void* const* d_in, const int* in_sizes, int n_in,
                              void* d_out, int out_size, void* d_ws, size_t ws_size,
                              hipStream_t stream) {
    const float* x     = (const float*)d_in[0];
    const float* w1    = (const float*)d_in[1];
    const float* b1    = (const float*)d_in[2];
    const float* gn1_w = (const float*)d_in[3];
    const float* gn1_b = (const float*)d_in[4];
    const float* w2    = (const float*)d_in[5];
    const float* b2    = (const float*)d_in[6];
    const float* gn2_w = (const float*)d_in[7];
    const float* gn2_b = (const float*)d_in[8];
    float* out = (float*)d_out;

    int*   valid  = (int*)d_ws;                 // 16384 ints
    int*   flag   = valid + N_ * C_;            // 32 * 32 ints (128B stride)
    float* pooled = (float*)(flag + N_ * 32);   // 16384 floats
    float* gate   = pooled + N_ * C_;           // 16384 floats

    // zero rendezvous state each call (deterministic, graph-capturable)
    hipMemsetAsync(valid, 0, (N_ * C_ + N_ * 32) * sizeof(int), stream);

    fused_kernel<<<N_ * C_, 256, 0, stream>>>(x, w1, b1, gn1_w, gn1_b,
                                              w2, b2, gn2_w, gn2_b,
                                              valid, flag, pooled, gate, out);
}

// Round 6
// 110.818 us; speedup vs baseline: 121.3579x; 15.0846x over previous
//
#include <hip/hip_runtime.h>
#include <math.h>

#define N_ 32
#define C_ 512
#define CR_ 64
#define HW_ 3136
#define HW4_ 784
constexpr float EPS = 1e-5f;

typedef float f4 __attribute__((ext_vector_type(4)));

// ---------------- Kernel 1: global average pool ----------------
// One block per (n,c) row; ascending order streams x into L3.
__global__ __launch_bounds__(256) void pool_kernel(const float* __restrict__ x,
                                                   float* __restrict__ pooled) {
    const int row = blockIdx.x;  // n*C + c
    const f4* xr = reinterpret_cast<const f4*>(x + (size_t)row * HW_);
    float acc = 0.f;
    for (int j = threadIdx.x; j < HW4_; j += 256) {
        f4 v = xr[j];
        acc += (v.x + v.y) + (v.z + v.w);
    }
    for (int o = 32; o; o >>= 1) acc += __shfl_down(acc, o, 64);
    __shared__ float s[4];
    if ((threadIdx.x & 63) == 0) s[threadIdx.x >> 6] = acc;
    __syncthreads();
    if (threadIdx.x == 0) {
        pooled[row] = (s[0] + s[1] + s[2] + s[3]) * (1.0f / HW_);
    }
}

// ---------------- Kernel 2: tiny MLP + GN + gate ----------------
__global__ __launch_bounds__(512) void gate_kernel(
    const float* __restrict__ pooled,
    const float* __restrict__ w1, const float* __restrict__ b1,
    const float* __restrict__ gn1_w, const float* __restrict__ gn1_b,
    const float* __restrict__ w2, const float* __restrict__ b2,
    const float* __restrict__ gn2_w, const float* __restrict__ gn2_b,
    float* __restrict__ gate)
{
    const int n = blockIdx.x;
    const int tid = threadIdx.x;
    __shared__ float sp[C_];
    __shared__ float sh[CR_];
    __shared__ float sred[8];

    sp[tid] = pooled[n * C_ + tid];
    __syncthreads();

    // h[r] = dot(pooled, w1[r,:]) + b1[r] ; 8 threads per output r
    {
        const int r = tid >> 3;
        const int l8 = tid & 7;
        float acc = 0.f;
        for (int c = l8; c < C_; c += 8) acc += sp[c] * w1[r * C_ + c];
        acc += __shfl_xor(acc, 1, 64);
        acc += __shfl_xor(acc, 2, 64);
        acc += __shfl_xor(acc, 4, 64);
        if (l8 == 0) sh[r] = acc + b1[r];
    }
    __syncthreads();

    // GroupNorm(1) over 64 + ELU (first wave)
    if (tid < 64) {
        float v = sh[tid];
        float s = v;
        for (int o = 32; o; o >>= 1) s += __shfl_xor(s, o, 64);
        const float mu = s * (1.0f / CR_);
        const float d = v - mu;
        float vv = d * d;
        for (int o = 32; o; o >>= 1) vv += __shfl_xor(vv, o, 64);
        float xn = d * rsqrtf(vv * (1.0f / CR_) + EPS) * gn1_w[tid] + gn1_b[tid];
        sh[tid] = xn > 0.f ? xn : expm1f(xn);  // ELU alpha=1
    }
    __syncthreads();

    // g[c] = dot(sh, w2[c,:]) + b2[c]
    float g = b2[tid];
    #pragma unroll 8
    for (int r = 0; r < CR_; ++r) g += sh[r] * w2[tid * CR_ + r];

    // GroupNorm(1) over 512
    float s = g;
    for (int o = 32; o; o >>= 1) s += __shfl_xor(s, o, 64);
    if ((tid & 63) == 0) sred[tid >> 6] = s;
    __syncthreads();
    const float mu = (sred[0] + sred[1] + sred[2] + sred[3] +
                      sred[4] + sred[5] + sred[6] + sred[7]) * (1.0f / C_);
    const float d = g - mu;
    float vv = d * d;
    for (int o = 32; o; o >>= 1) vv += __shfl_xor(vv, o, 64);
    __syncthreads();
    if ((tid & 63) == 0) sred[tid >> 6] = vv;
    __syncthreads();
    const float var = (sred[0] + sred[1] + sred[2] + sred[3] +
                       sred[4] + sred[5] + sred[6] + sred[7]) * (1.0f / C_);
    float xn = d * rsqrtf(var + EPS) * gn2_w[tid] + gn2_b[tid];
    gate[n * C_ + tid] = 1.0f / (1.0f + expf(-xn));
}

// ---------------- Kernel 3: broadcast scale (REVERSE row order) ----------------
// Pool filled L3 in ascending row order; consuming rows in DESCENDING order
// reads most-recently-cached lines first (LRU-friendly). nt stores keep the
// output stream from evicting x.
__global__ __launch_bounds__(256) void scale_kernel(const float* __restrict__ x,
                                                    const float* __restrict__ gate,
                                                    float* __restrict__ out) {
    const int row = (N_ * C_ - 1) - blockIdx.x;
    const float g = gate[row];
    const f4* xr = reinterpret_cast<const f4*>(x + (size_t)row * HW_);
    f4* orow = reinterpret_cast<f4*>(out + (size_t)row * HW_);
    for (int j = threadIdx.x; j < HW4_; j += 256) {
        f4 v = xr[j];
        v.x *= g; v.y *= g; v.z *= g; v.w *= g;
        __builtin_nontemporal_store(v, &orow[j]);
    }
}

extern "C" void kernel_launch(void* const* d_in, const int* in_sizes, int n_in,
                              void* d_out, int out_size, void* d_ws, size_t ws_size,
                              hipStream_t stream) {
    const float* x     = (const float*)d_in[0];
    const float* w1    = (const float*)d_in[1];
    const float* b1    = (const float*)d_in[2];
    const float* gn1_w = (const float*)d_in[3];
    const float* gn1_b = (const float*)d_in[4];
    const float* w2    = (const float*)d_in[5];
    const float* b2    = (const float*)d_in[6];
    const float* gn2_w = (const float*)d_in[7];
    const float* gn2_b = (const float*)d_in[8];
    float* out = (float*)d_out;

    float* pooled = (float*)d_ws;          // 32*512 floats
    float* gate   = pooled + N_ * C_;      // 32*512 floats

    pool_kernel<<<N_ * C_, 256, 0, stream>>>(x, pooled);
    gate_kernel<<<N_, 512, 0, stream>>>(pooled, w1, b1, gn1_w, gn1_b,
                                        w2, b2, gn2_w, gn2_b, gate);
    scale_kernel<<<N_ * C_, 256, 0, stream>>>(x, gate, out);
}